// Round 3
// baseline (679.051 us; speedup 1.0000x reference)
//
#include <hip/hip_runtime.h>

typedef unsigned short u16;
typedef unsigned int   u32;

#define BB 4
#define CCH 64
#define HH 180
#define WWD 320
#define HW_ 57600            // H*W
#define TENSOR_ 14745600     // B*C*H*W
#define LDSP 42              // padded LDS row stride (floats)

// ---- module-scope scratch ----
__device__ u32 g_isbf16;                        // dtype flag (recomputed every call)
__device__ __align__(16) float g_gap[512];      // [side][b][c]
__device__ __align__(16) float g_att[24];       // [side][b][k]
__device__ __align__(16) float g_bagg[512];     // [side][b][o]
__device__ __align__(16) float g_swn[128];      // [side][o]
__device__ __align__(16) float g_sb[128];       // [side][o]
__device__ __align__(16) float g_wagg[32768];   // [side][b][o][i] fp32
__device__ __align__(16) float g_w1f[8192];     // LN-folded p1 weights fp32
__device__ __align__(16) float g_w2f[8192];     // p2 weights fp32
__device__ __align__(16) float g_p1b[128];      // [side][o]
__device__ __align__(16) float g_p2b[128];      // [side][o]
__device__ __align__(16) float g_bg[128];       // side0: beta, side1: gamma

__device__ __forceinline__ float b2f(u32 u) {
    union { u32 i; float f; } v; v.i = u << 16; return v.f;
}
__device__ __forceinline__ u16 f2b(float f) {
    union { float f; u32 i; } v; v.f = f;
    return (u16)((v.i + 0x7fffu + ((v.i >> 16) & 1u)) >> 16);   // RNE
}
__device__ __forceinline__ float ldg1(const void* p, int i, bool bf) {
    return bf ? b2f(((const u16*)p)[i]) : ((const float*)p)[i];
}

// ---------------- kernel 0: detect input dtype from x_l bit patterns
__global__ __launch_bounds__(256) void detect_kernel(const u32* __restrict__ x) {
    __shared__ int cnt;
    if (threadIdx.x == 0) cnt = 0;
    __syncthreads();
    u32 w = x[threadIdx.x];
    u32 v = w & 0xffffu;              // low u16: bf16 element (bf16 flavor) or fp32 mantissa bits
    u32 e = (v >> 7) & 0xffu;
    int ok = (e == 0u) || (e >= 0x68u && e <= 0x8eu);
    atomicAdd(&cnt, ok);
    __syncthreads();
    if (threadIdx.x == 0) g_isbf16 = (cnt > 128) ? 1u : 0u;
}

// ---------------- kernel 1: global average pool of x_l / x_r -> g_gap
__global__ __launch_bounds__(256) void gap_kernel(const void* __restrict__ xl,
                                                  const void* __restrict__ xr) {
    bool bf = (g_isbf16 != 0u);
    int job = blockIdx.x;                 // side*256 + b*64 + c
    int side = job >> 8;
    int bc = job & 255;
    float s = 0.f;
    if (bf) {
        const u16* src = (const u16*)(side ? xr : xl) + (size_t)bc * HW_;
        const uint4* p = (const uint4*)src;   // 7200 vectors of 8 bf16
        for (int i = threadIdx.x; i < 7200; i += 256) {
            uint4 v = p[i];
            s += b2f(v.x & 0xffffu) + b2f(v.x >> 16)
               + b2f(v.y & 0xffffu) + b2f(v.y >> 16)
               + b2f(v.z & 0xffffu) + b2f(v.z >> 16)
               + b2f(v.w & 0xffffu) + b2f(v.w >> 16);
        }
    } else {
        const float* src = (const float*)(side ? xr : xl) + (size_t)bc * HW_;
        const float4* p = (const float4*)src; // 14400 vectors of 4 fp32
        for (int i = threadIdx.x; i < 14400; i += 256) {
            float4 v = p[i];
            s += v.x + v.y + v.z + v.w;
        }
    }
    #pragma unroll
    for (int off = 32; off > 0; off >>= 1) s += __shfl_down(s, off, 64);
    __shared__ float red[4];
    int lane = threadIdx.x & 63, wv = threadIdx.x >> 6;
    if (lane == 0) red[wv] = s;
    __syncthreads();
    if (threadIdx.x == 0)
        g_gap[job] = (red[0] + red[1] + red[2] + red[3]) * (1.f / 57600.f);
}

// ---------------- kernel 2a: expert attention, weight conversion, bagg
__global__ __launch_bounds__(256) void prep1_kernel(
    const void* __restrict__ nlw, const void* __restrict__ nlb,
    const void* __restrict__ nrw, const void* __restrict__ nrb,
    const void* __restrict__ lp1w, const void* __restrict__ lp1b,
    const void* __restrict__ rp1w, const void* __restrict__ rp1b,
    const void* __restrict__ lp2w, const void* __restrict__ lp2b,
    const void* __restrict__ rp2w, const void* __restrict__ rp2b,
    const void* __restrict__ beta, const void* __restrict__ gamma,
    const void* __restrict__ lf1w, const void* __restrict__ lf1b,
    const void* __restrict__ lf2w, const void* __restrict__ lf2b,
    const void* __restrict__ lfbias,
    const void* __restrict__ rf1w, const void* __restrict__ rf1b,
    const void* __restrict__ rf2w, const void* __restrict__ rf2b,
    const void* __restrict__ rfbias)
{
    bool bf = (g_isbf16 != 0u);
    __shared__ float att[2][4][3];
    int t = threadIdx.x;
    if (t < 8) {
        int side = t >> 2, b = t & 3;
        const void* f1w = side ? rf1w : lf1w;
        const void* f1b = side ? rf1b : lf1b;
        const void* f2w = side ? rf2w : lf2w;
        const void* f2bv = side ? rf2b : lf2b;
        const float* g = g_gap + side*256 + b*64;
        float a1[3];
        for (int k = 0; k < 3; k++) {
            float s = ldg1(f1b, k, bf);
            for (int c = 0; c < 64; c++) s += g[c] * ldg1(f1w, k*64 + c, bf);
            a1[k] = fmaxf(s, 0.f);
        }
        float a2[3];
        for (int j = 0; j < 3; j++) {
            float s = ldg1(f2bv, j, bf);
            for (int k = 0; k < 3; k++) s += a1[k] * ldg1(f2w, j*3 + k, bf);
            a2[j] = s;
        }
        float m = fmaxf(fmaxf(a2[0], a2[1]), a2[2]);
        float e0 = __expf(a2[0]-m), e1 = __expf(a2[1]-m), e2 = __expf(a2[2]-m);
        float inv = 1.f / (e0 + e1 + e2);
        att[side][b][0] = e0*inv; att[side][b][1] = e1*inv; att[side][b][2] = e2*inv;
        g_att[(side*4+b)*3+0] = e0*inv;
        g_att[(side*4+b)*3+1] = e1*inv;
        g_att[(side*4+b)*3+2] = e2*inv;
    }
    if (t < 128) {
        int side = t >> 6, o = t & 63;
        const void* w1 = side ? rp1w : lp1w;
        const void* w2 = side ? rp2w : lp2w;
        const void* nw = side ? nrw : nlw;
        const void* nb = side ? nrb : nlb;
        float s_wn = 0.f, s_b = 0.f;
        for (int i = 0; i < 64; i++) {
            float wf = ldg1(w1, o*64 + i, bf);
            float wp = wf * ldg1(nw, i, bf);
            g_w1f[side*4096 + o*64 + i] = wp;
            s_wn += wp;
            s_b  += wf * ldg1(nb, i, bf);
            g_w2f[side*4096 + o*64 + i] = ldg1(w2, o*64 + i, bf);
        }
        g_swn[side*64 + o] = s_wn;
        g_sb[side*64 + o]  = s_b;
        g_p1b[t] = ldg1(side ? rp1b : lp1b, o, bf);
        g_p2b[t] = ldg1(side ? rp2b : lp2b, o, bf);
        g_bg[t]  = ldg1(side ? gamma : beta, o, bf);
    }
    __syncthreads();
    for (int idx = t; idx < 512; idx += 256) {
        int side = idx >> 8, r = idx & 255, b = r >> 6, o = r & 63;
        const void* bp = side ? rfbias : lfbias;
        g_bagg[idx] = att[side][b][0]*ldg1(bp, o, bf)
                    + att[side][b][1]*ldg1(bp, 64+o, bf)
                    + att[side][b][2]*ldg1(bp, 128+o, bf);
    }
}

// ---------------- kernel 2b: Wagg[side][b][o][i] = sum_k att*W[k]
__global__ __launch_bounds__(256) void prep2_kernel(const void* __restrict__ lfW,
                                                    const void* __restrict__ rfW) {
    bool bf = (g_isbf16 != 0u);
    int idx = blockIdx.x * 2048 + threadIdx.x * 8;   // 16 blocks cover 32768
    int side = idx >> 14, r = idx & 16383, b = r >> 12, oi = r & 4095;
    const void* Wp = side ? rfW : lfW;
    float a0 = g_att[(side*4+b)*3+0];
    float a1 = g_att[(side*4+b)*3+1];
    float a2 = g_att[(side*4+b)*3+2];
    #pragma unroll
    for (int q = 0; q < 8; q++)
        g_wagg[idx+q] = a0*ldg1(Wp, oi+q, bf) + a1*ldg1(Wp, 4096+oi+q, bf)
                      + a2*ldg1(Wp, 8192+oi+q, bf);
}

// ---------------- kernel 3: fused LN->proj->cross-attn->dynamic conv->residual
// one block = one (b,h) row x 4 width-chunks (40 pixels); 256 threads = 4 waves
__global__ __launch_bounds__(256) void main_kernel(
    const void* __restrict__ xl_g, const void* __restrict__ xr_g,
    void* __restrict__ outv)
{
    __shared__ __align__(16) float xl[64*LDSP];
    __shared__ __align__(16) float xr[64*LDSP];
    __shared__ __align__(16) float Qa[64*LDSP];   // Ql, then F_r2l*beta
    __shared__ __align__(16) float Qb[64*LDSP];   // Qr, then F_l2r*gamma
    __shared__ float attn[4][10][10];
    __shared__ float Ar[4][10][10];   // softmax over v
    __shared__ float Al[4][10][10];   // softmax over u
    __shared__ float muL[40], rsL[40], muR[40], rsR[40];

    bool bf = (g_isbf16 != 0u);
    int t = threadIdx.x;
    int bid = blockIdx.x;
    int b  = bid / (HH*8);
    int r0 = bid % (HH*8);
    int h  = r0 / 8;
    int g  = r0 % 8;
    int w0 = g * 40;

    // ---- P0: load 64x40 tiles of x_l, x_r -> fp32 LDS ----
    if (bf) {
        for (int idx = t; idx < 640; idx += 256) {
            int tensor = idx / 320;
            int r2 = idx - tensor*320;
            int c = r2 / 5, seg = r2 - c*5;
            const u16* src = (const u16*)(tensor ? xr_g : xl_g);
            uint4 v = *(const uint4*)(src + (((size_t)(b*64+c)*HH + h)*WWD + w0 + seg*8));
            float2* d2 = (float2*)((tensor ? xr : xl) + c*LDSP + seg*8);
            d2[0] = make_float2(b2f(v.x & 0xffffu), b2f(v.x >> 16));
            d2[1] = make_float2(b2f(v.y & 0xffffu), b2f(v.y >> 16));
            d2[2] = make_float2(b2f(v.z & 0xffffu), b2f(v.z >> 16));
            d2[3] = make_float2(b2f(v.w & 0xffffu), b2f(v.w >> 16));
        }
    } else {
        for (int idx = t; idx < 1280; idx += 256) {
            int tensor = idx / 640;
            int r2 = idx - tensor*640;
            int c = r2 / 10, seg = r2 - c*10;
            const float* src = (const float*)(tensor ? xr_g : xl_g);
            float4 v = *(const float4*)(src + (((size_t)(b*64+c)*HH + h)*WWD + w0 + seg*4));
            float2* d2 = (float2*)((tensor ? xr : xl) + c*LDSP + seg*4);
            d2[0] = make_float2(v.x, v.y);
            d2[1] = make_float2(v.z, v.w);
        }
    }
    __syncthreads();

    // ---- P1: channel-LN stats per pixel ----
    if (t < 128 && (t & 63) < 40) {
        int side = t >> 6;
        int u = t & 63;
        const float* xx = side ? xr : xl;
        float s = 0.f, s2 = 0.f;
        for (int c = 0; c < 64; c++) { float v = xx[c*LDSP + u]; s += v; s2 += v*v; }
        float mu = s * (1.f/64.f);
        float var = fmaxf(s2 * (1.f/64.f) - mu*mu, 0.f);
        float rs = rsqrtf(var + 1e-6f);
        if (side) { muR[u] = mu; rsR[u] = rs; } else { muL[u] = mu; rsL[u] = rs; }
    }
    __syncthreads();

    // ---- P2: 4 GEMMs, register-blocked 4(o) x 10(u) per lane ----
    int wv   = t >> 6;        // wave: 0=Ql 1=Qr 2=Vl 3=Vr
    int lane = t & 63;
    int og = lane & 15, ug = lane >> 4;
    int ob = og * 4;          // 4 output channels
    int ub = ug * 10;         // 10 pixels (one width chunk)

    float acc[4][10];
    #pragma unroll
    for (int r = 0; r < 4; r++)
        #pragma unroll
        for (int u = 0; u < 10; u++) acc[r][u] = 0.f;

    {
        const float* wmat; const float* xsrc;
        switch (wv) {
            case 0:  wmat = g_w1f;        xsrc = xl; break;
            case 1:  wmat = g_w1f + 4096; xsrc = xr; break;
            case 2:  wmat = g_w2f;        xsrc = xl; break;
            default: wmat = g_w2f + 4096; xsrc = xr; break;
        }
        for (int ii = 0; ii < 16; ii++) {
            float4 wv4[4];
            #pragma unroll
            for (int r = 0; r < 4; r++)
                wv4[r] = *(const float4*)(wmat + (ob+r)*64 + ii*4);
            #pragma unroll
            for (int j = 0; j < 4; j++) {
                int i = ii*4 + j;
                const float2* xp = (const float2*)(xsrc + i*LDSP + ub);
                float2 x01 = xp[0], x23 = xp[1], x45 = xp[2], x67 = xp[3], x89 = xp[4];
                float x10[10] = {x01.x,x01.y,x23.x,x23.y,x45.x,x45.y,x67.x,x67.y,x89.x,x89.y};
                #pragma unroll
                for (int r = 0; r < 4; r++) {
                    float wf = ((const float*)&wv4[r])[j];
                    #pragma unroll
                    for (int u = 0; u < 10; u++) acc[r][u] += wf * x10[u];
                }
            }
        }
    }

    if (wv < 2) {   // Q epilogue (LN fold) -> LDS
        const float* mu  = wv ? muR : muL;
        const float* rs  = wv ? rsR : rsL;
        const float* sw_ = g_swn + wv*64;
        const float* sb_ = g_sb  + wv*64;
        float* dst = wv ? Qb : Qa;
        #pragma unroll
        for (int r = 0; r < 4; r++) {
            int o = ob + r;
            float sw = sw_[o], sbv = sb_[o] + g_p1b[wv*64 + o];
            #pragma unroll
            for (int u = 0; u < 10; u++) {
                int uu = ub + u;
                dst[o*LDSP + uu] = rs[uu]*(acc[r][u] - mu[uu]*sw) + sbv;
            }
        }
    } else {        // V: add bias, keep in registers
        #pragma unroll
        for (int r = 0; r < 4; r++) {
            float bv = g_p2b[(wv-2)*64 + ob + r];
            #pragma unroll
            for (int u = 0; u < 10; u++) acc[r][u] += bv;
        }
    }
    __syncthreads();

    // ---- P3: block-diag attention, wave k = chunk k ----
    {
        int k = wv;
        for (int p = lane; p < 100; p += 64) {
            int uu = p / 10, vvv = p - uu*10;
            const float* qa = Qa + k*10 + uu;
            const float* qb = Qb + k*10 + vvv;
            float s = 0.f;
            #pragma unroll 8
            for (int c = 0; c < 64; c++) s += qa[c*LDSP] * qb[c*LDSP];
            attn[k][uu][vvv] = s * 0.125f;   // scale = C^-0.5
        }
    }
    __syncthreads();
    if (t < 40) {                      // softmax over v -> Ar
        int k = t / 10, uu = t - (t/10)*10;
        float m = attn[k][uu][0];
        #pragma unroll
        for (int v2 = 1; v2 < 10; v2++) m = fmaxf(m, attn[k][uu][v2]);
        float e[10]; float ssum = 0.f;
        #pragma unroll
        for (int v2 = 0; v2 < 10; v2++) { e[v2] = __expf(attn[k][uu][v2] - m); ssum += e[v2]; }
        float inv = 1.f / ssum;
        #pragma unroll
        for (int v2 = 0; v2 < 10; v2++) Ar[k][uu][v2] = e[v2]*inv;
    } else if (t >= 64 && t < 104) {   // softmax over u -> Al
        int t2 = t - 64;
        int k = t2 / 10, vvv = t2 - (t2/10)*10;
        float m = attn[k][0][vvv];
        #pragma unroll
        for (int u2 = 1; u2 < 10; u2++) m = fmaxf(m, attn[k][u2][vvv]);
        float e[10]; float ssum = 0.f;
        #pragma unroll
        for (int u2 = 0; u2 < 10; u2++) { e[u2] = __expf(attn[k][u2][vvv] - m); ssum += e[u2]; }
        float inv = 1.f / ssum;
        #pragma unroll
        for (int u2 = 0; u2 < 10; u2++) Al[k][u2][vvv] = e[u2]*inv;
    }
    __syncthreads();

    // ---- P4: F from register-resident V (waves 2,3) ----
    if (wv == 3) {          // F_r2l = Ar @ Vr^T, *beta -> Qa
        int k = ug;
        #pragma unroll
        for (int r = 0; r < 4; r++) {
            float scv = g_bg[ob + r];          // beta (side 0 output)
            #pragma unroll
            for (int uu = 0; uu < 10; uu++) {
                float s = 0.f;
                #pragma unroll
                for (int v2 = 0; v2 < 10; v2++) s += Ar[k][uu][v2] * acc[r][v2];
                Qa[(ob+r)*LDSP + ub + uu] = s * scv;
            }
        }
    } else if (wv == 2) {   // F_l2r = Al^T @ Vl, *gamma -> Qb
        int k = ug;
        #pragma unroll
        for (int r = 0; r < 4; r++) {
            float scv = g_bg[64 + ob + r];     // gamma (side 1 output)
            #pragma unroll
            for (int vvv = 0; vvv < 10; vvv++) {
                float s = 0.f;
                #pragma unroll
                for (int u2 = 0; u2 < 10; u2++) s += Al[k][u2][vvv] * acc[r][u2];
                Qb[(ob+r)*LDSP + ub + vvv] = s * scv;
            }
        }
    }
    __syncthreads();

    // ---- P5: dynamic conv + residual + store (waves 0,1; wave = output side) ----
    if (wv < 2) {
        int side = wv;
        const float* F  = side ? Qb : Qa;
        const float* xs = side ? xr : xl;
        const float* wrow = g_wagg + (size_t)(side*4 + b)*4096;
        float acc5[4][10];
        #pragma unroll
        for (int r = 0; r < 4; r++)
            #pragma unroll
            for (int u = 0; u < 10; u++) acc5[r][u] = 0.f;
        for (int ic = 0; ic < 16; ic++) {
            float4 wv4[4];
            #pragma unroll
            for (int r = 0; r < 4; r++)
                wv4[r] = *(const float4*)(wrow + (ob+r)*64 + ic*4);
            #pragma unroll
            for (int j = 0; j < 4; j++) {
                int i = ic*4 + j;
                const float2* xp = (const float2*)(F + i*LDSP + ub);
                float2 x01 = xp[0], x23 = xp[1], x45 = xp[2], x67 = xp[3], x89 = xp[4];
                float x10[10] = {x01.x,x01.y,x23.x,x23.y,x45.x,x45.y,x67.x,x67.y,x89.x,x89.y};
                #pragma unroll
                for (int r = 0; r < 4; r++) {
                    float wf = ((const float*)&wv4[r])[j];
                    #pragma unroll
                    for (int u = 0; u < 10; u++) acc5[r][u] += wf * x10[u];
                }
            }
        }
        #pragma unroll
        for (int r = 0; r < 4; r++) {
            int o = ob + r;
            float bg = g_bagg[side*256 + b*64 + o];
            size_t off = (size_t)side*TENSOR_ + (((size_t)(b*64+o)*HH + h)*WWD + w0 + ub);
            if (bf) {
                u32* op32 = (u32*)((u16*)outv + off);
                #pragma unroll
                for (int q = 0; q < 5; q++) {
                    float f0 = acc5[r][2*q]   + bg + xs[o*LDSP + ub + 2*q];
                    float f1 = acc5[r][2*q+1] + bg + xs[o*LDSP + ub + 2*q+1];
                    op32[q] = (u32)f2b(f0) | ((u32)f2b(f1) << 16);
                }
            } else {
                float2* opf = (float2*)((float*)outv + off);
                #pragma unroll
                for (int q = 0; q < 5; q++) {
                    float f0 = acc5[r][2*q]   + bg + xs[o*LDSP + ub + 2*q];
                    float f1 = acc5[r][2*q+1] + bg + xs[o*LDSP + ub + 2*q+1];
                    opf[q] = make_float2(f0, f1);
                }
            }
        }
    }
}

extern "C" void kernel_launch(void* const* d_in, const int* in_sizes, int n_in,
                              void* d_out, int out_size, void* d_ws, size_t ws_size,
                              hipStream_t stream) {
    (void)in_sizes; (void)n_in; (void)out_size; (void)d_ws; (void)ws_size;
    const void* x_l  = d_in[0];
    const void* x_r  = d_in[1];

    detect_kernel<<<1, 256, 0, stream>>>((const u32*)x_l);
    gap_kernel<<<512, 256, 0, stream>>>(x_l, x_r);
    prep1_kernel<<<1, 256, 0, stream>>>(
        d_in[2], d_in[3], d_in[4], d_in[5],      // norm l/r w,b
        d_in[6], d_in[7], d_in[8], d_in[9],      // lp1 w,b  rp1 w,b
        d_in[10], d_in[11], d_in[12], d_in[13],  // lp2 w,b  rp2 w,b
        d_in[14], d_in[15],                      // beta, gamma
        d_in[16], d_in[17], d_in[18], d_in[19], d_in[21],  // lf fc1w,fc1b,fc2w,fc2b,bias
        d_in[22], d_in[23], d_in[24], d_in[25], d_in[27]); // rf fc1w,fc1b,fc2w,fc2b,bias
    prep2_kernel<<<16, 256, 0, stream>>>(d_in[20], d_in[26]);
    main_kernel<<<BB*HH*8, 256, 0, stream>>>(x_l, x_r, d_out);
}

// Round 4
// 640.390 us; speedup vs baseline: 1.0604x; 1.0604x over previous
//
#include <hip/hip_runtime.h>

typedef unsigned int u32;

#define BB 4
#define HH 180
#define WWD 320
#define HW_ 57600            // H*W
#define TENSOR_ 14745600     // B*C*H*W
#define LDSP 42              // padded LDS row stride (floats)

// ---- module-scope scratch ----
__device__ __align__(16) float g_gap[512];      // [side][b][c]
__device__ __align__(16) float g_bagg[512];     // [side][b][o]
__device__ __align__(16) float g_swn[128];      // [side][o]
__device__ __align__(16) float g_sb[128];       // [side][o]
__device__ __align__(16) float g_wagg[32768];   // [side][b][o][i]
__device__ __align__(16) float g_w1f[8192];     // LN-folded p1 weights

// ---------------- kernel 1: global average pool of x_l / x_r -> g_gap
__global__ __launch_bounds__(256) void gap_kernel(const float* __restrict__ xl,
                                                  const float* __restrict__ xr) {
    int job = blockIdx.x;                 // side*256 + b*64 + c
    int side = job >> 8;
    int bc = job & 255;
    const float4* p = (const float4*)((side ? xr : xl) + (size_t)bc * HW_);
    float s = 0.f;
    for (int i = threadIdx.x; i < 14400; i += 256) {
        float4 v = p[i];
        s += v.x + v.y + v.z + v.w;
    }
    #pragma unroll
    for (int off = 32; off > 0; off >>= 1) s += __shfl_down(s, off, 64);
    __shared__ float red[4];
    int lane = threadIdx.x & 63, wv = threadIdx.x >> 6;
    if (lane == 0) red[wv] = s;
    __syncthreads();
    if (threadIdx.x == 0)
        g_gap[job] = (red[0] + red[1] + red[2] + red[3]) * (1.f / 57600.f);
}

// ---------------- kernel 2: expert mixture + folded weights + wagg + bagg
// blocks 0..15: wagg slices; block 16: w1f/swn/sb/bagg. Every block recomputes att.
__global__ __launch_bounds__(256) void prep_kernel(
    const float* __restrict__ nlw, const float* __restrict__ nlb,
    const float* __restrict__ nrw, const float* __restrict__ nrb,
    const float* __restrict__ lp1w, const float* __restrict__ rp1w,
    const float* __restrict__ lf1w, const float* __restrict__ lf1b,
    const float* __restrict__ lf2w, const float* __restrict__ lf2b,
    const float* __restrict__ lfbias,
    const float* __restrict__ rf1w, const float* __restrict__ rf1b,
    const float* __restrict__ rf2w, const float* __restrict__ rf2b,
    const float* __restrict__ rfbias,
    const float* __restrict__ lfW, const float* __restrict__ rfW)
{
    __shared__ float att[2][4][3];
    int t = threadIdx.x;
    if (t < 8) {
        int side = t >> 2, b = t & 3;
        const float* f1w = side ? rf1w : lf1w;
        const float* f1b = side ? rf1b : lf1b;
        const float* f2w = side ? rf2w : lf2w;
        const float* f2bv = side ? rf2b : lf2b;
        const float* g = g_gap + side*256 + b*64;
        float a1[3];
        #pragma unroll
        for (int k = 0; k < 3; k++) {
            float s = f1b[k];
            for (int c = 0; c < 64; c++) s += g[c] * f1w[k*64 + c];
            a1[k] = fmaxf(s, 0.f);
        }
        float a2[3];
        #pragma unroll
        for (int j = 0; j < 3; j++) {
            float s = f2bv[j];
            #pragma unroll
            for (int k = 0; k < 3; k++) s += a1[k] * f2w[j*3 + k];
            a2[j] = s;
        }
        float m = fmaxf(fmaxf(a2[0], a2[1]), a2[2]);
        float e0 = __expf(a2[0]-m), e1 = __expf(a2[1]-m), e2 = __expf(a2[2]-m);
        float inv = 1.f / (e0 + e1 + e2);
        att[side][b][0] = e0*inv; att[side][b][1] = e1*inv; att[side][b][2] = e2*inv;
    }
    __syncthreads();

    if (blockIdx.x < 16) {
        int idx = blockIdx.x * 2048 + t * 8;
        int side = idx >> 14, r = idx & 16383, b = r >> 12, oi = r & 4095;
        const float* Wp = side ? rfW : lfW;
        float a0 = att[side][b][0], a1 = att[side][b][1], a2 = att[side][b][2];
        #pragma unroll
        for (int q = 0; q < 8; q++)
            g_wagg[idx+q] = a0*Wp[oi+q] + a1*Wp[4096+oi+q] + a2*Wp[8192+oi+q];
    } else {
        if (t < 128) {
            int side = t >> 6, o = t & 63;
            const float* w1 = side ? rp1w : lp1w;
            const float* nw = side ? nrw : nlw;
            const float* nb = side ? nrb : nlb;
            float s_wn = 0.f, s_b = 0.f;
            for (int i = 0; i < 64; i++) {
                float wf = w1[o*64 + i];
                float wp = wf * nw[i];
                g_w1f[side*4096 + o*64 + i] = wp;
                s_wn += wp;
                s_b  += wf * nb[i];
            }
            g_swn[side*64 + o] = s_wn;
            g_sb[side*64 + o]  = s_b;
        }
        for (int idx = t; idx < 512; idx += 256) {
            int side = idx >> 8, r = idx & 255, b = r >> 6, o = r & 63;
            const float* bp = side ? rfbias : lfbias;
            g_bagg[idx] = att[side][b][0]*bp[o]
                        + att[side][b][1]*bp[64+o]
                        + att[side][b][2]*bp[128+o];
        }
    }
}

// ---------------- kernel 3: fused LN->proj->cross-attn->dynamic conv->residual
// one block = one (b,h) row x 4 width-chunks (40 pixels); 256 threads = 4 waves
// LDS reuse: xt0: x_l -> Ql -> F_r2l*beta ; xt1: x_r -> Qr -> F_l2r*gamma
__global__ __launch_bounds__(256, 4) void main_kernel(
    const float* __restrict__ xl_g, const float* __restrict__ xr_g,
    const float* __restrict__ lp1b, const float* __restrict__ rp1b,
    const float* __restrict__ lp2w, const float* __restrict__ lp2b,
    const float* __restrict__ rp2w, const float* __restrict__ rp2b,
    const float* __restrict__ beta, const float* __restrict__ gamma,
    float* __restrict__ out)
{
    __shared__ __align__(16) float xt0[64*LDSP];
    __shared__ __align__(16) float xt1[64*LDSP];
    __shared__ float attn[4][10][10];
    __shared__ float Ar[4][10][10];   // softmax over v
    __shared__ float Al[4][10][10];   // softmax over u
    __shared__ float muL[40], rsL[40], muR[40], rsR[40];

    int t = threadIdx.x;
    int bid = blockIdx.x;
    int b  = bid / (HH*8);
    int r0 = bid % (HH*8);
    int h  = r0 / 8;
    int g  = r0 % 8;
    int w0 = g * 40;

    // ---- P0: load 64x40 fp32 tiles ----
    for (int idx = t; idx < 1280; idx += 256) {
        int tensor = idx / 640;
        int r2 = idx - tensor*640;
        int c = r2 / 10, seg = r2 - c*10;
        const float* src = tensor ? xr_g : xl_g;
        float4 v = *(const float4*)(src + (((size_t)(b*64+c)*HH + h)*WWD + w0 + seg*4));
        float2* d2 = (float2*)((tensor ? xt1 : xt0) + c*LDSP + seg*4);
        d2[0] = make_float2(v.x, v.y);
        d2[1] = make_float2(v.z, v.w);
    }
    __syncthreads();

    // ---- P1: channel-LN stats per pixel ----
    if (t < 128 && (t & 63) < 40) {
        int side = t >> 6;
        int u = t & 63;
        const float* xx = side ? xt1 : xt0;
        float s = 0.f, s2 = 0.f;
        for (int c = 0; c < 64; c++) { float v = xx[c*LDSP + u]; s += v; s2 += v*v; }
        float mu = s * (1.f/64.f);
        float var = fmaxf(s2 * (1.f/64.f) - mu*mu, 0.f);
        float rs = rsqrtf(var + 1e-6f);
        if (side) { muR[u] = mu; rsR[u] = rs; } else { muL[u] = mu; rsL[u] = rs; }
    }
    __syncthreads();

    // ---- P2: 4 GEMMs, one per wave, register tile 4(o) x 10(u) ----
    int wv   = t >> 6;        // 0=Ql 1=Qr 2=Vl 3=Vr
    int lane = t & 63;
    int og = lane & 15, ug = lane >> 4;
    int ob = og * 4;
    int ub = ug * 10;

    float acc[4][10];
    #pragma unroll
    for (int r = 0; r < 4; r++)
        #pragma unroll
        for (int u = 0; u < 10; u++) acc[r][u] = 0.f;

    {
        const float* wmat; const float* xsrc;
        switch (wv) {
            case 0:  wmat = g_w1f;        xsrc = xt0; break;
            case 1:  wmat = g_w1f + 4096; xsrc = xt1; break;
            case 2:  wmat = lp2w;         xsrc = xt0; break;
            default: wmat = rp2w;         xsrc = xt1; break;
        }
        for (int ii = 0; ii < 16; ii++) {
            float4 wv4[4];
            #pragma unroll
            for (int r = 0; r < 4; r++)
                wv4[r] = *(const float4*)(wmat + (ob+r)*64 + ii*4);
            #pragma unroll
            for (int j = 0; j < 4; j++) {
                int i = ii*4 + j;
                const float2* xp = (const float2*)(xsrc + i*LDSP + ub);
                float2 x01 = xp[0], x23 = xp[1], x45 = xp[2], x67 = xp[3], x89 = xp[4];
                float x10[10] = {x01.x,x01.y,x23.x,x23.y,x45.x,x45.y,x67.x,x67.y,x89.x,x89.y};
                #pragma unroll
                for (int r = 0; r < 4; r++) {
                    float wf = ((const float*)&wv4[r])[j];
                    #pragma unroll
                    for (int u = 0; u < 10; u++) acc[r][u] += wf * x10[u];
                }
            }
        }
    }
    __syncthreads();   // all x reads complete before Q overwrites x

    if (wv < 2) {   // Q epilogue (LN fold) -> overwrite x tile in LDS
        const float* mu  = wv ? muR : muL;
        const float* rs  = wv ? rsR : rsL;
        const float* sw_ = g_swn + wv*64;
        const float* sb_ = g_sb  + wv*64;
        const float* p1b = wv ? rp1b : lp1b;
        float* dst = wv ? xt1 : xt0;
        #pragma unroll
        for (int r = 0; r < 4; r++) {
            int o = ob + r;
            float sw = sw_[o], sbv = sb_[o] + p1b[o];
            #pragma unroll
            for (int u = 0; u < 10; u++) {
                int uu = ub + u;
                dst[o*LDSP + uu] = rs[uu]*(acc[r][u] - mu[uu]*sw) + sbv;
            }
        }
    } else {        // V: add bias, keep in registers
        const float* p2b = (wv == 2) ? lp2b : rp2b;
        #pragma unroll
        for (int r = 0; r < 4; r++) {
            float bv = p2b[ob+r];
            #pragma unroll
            for (int u = 0; u < 10; u++) acc[r][u] += bv;
        }
    }
    __syncthreads();

    // ---- P3: block-diag attention, wave k = chunk k ----
    {
        int k = wv;
        for (int p = lane; p < 100; p += 64) {
            int uu = p / 10, vvv = p - uu*10;
            const float* qa = xt0 + k*10 + uu;
            const float* qb = xt1 + k*10 + vvv;
            float s = 0.f;
            #pragma unroll 8
            for (int c = 0; c < 64; c++) s += qa[c*LDSP] * qb[c*LDSP];
            attn[k][uu][vvv] = s * 0.125f;   // scale = C^-0.5
        }
    }
    __syncthreads();
    if (t < 40) {                      // softmax over v -> Ar
        int k = t / 10, uu = t - (t/10)*10;
        float m = attn[k][uu][0];
        #pragma unroll
        for (int v2 = 1; v2 < 10; v2++) m = fmaxf(m, attn[k][uu][v2]);
        float e[10]; float ssum = 0.f;
        #pragma unroll
        for (int v2 = 0; v2 < 10; v2++) { e[v2] = __expf(attn[k][uu][v2] - m); ssum += e[v2]; }
        float inv = 1.f / ssum;
        #pragma unroll
        for (int v2 = 0; v2 < 10; v2++) Ar[k][uu][v2] = e[v2]*inv;
    } else if (t >= 64 && t < 104) {   // softmax over u -> Al
        int t2 = t - 64;
        int k = t2 / 10, vvv = t2 - (t2/10)*10;
        float m = attn[k][0][vvv];
        #pragma unroll
        for (int u2 = 1; u2 < 10; u2++) m = fmaxf(m, attn[k][u2][vvv]);
        float e[10]; float ssum = 0.f;
        #pragma unroll
        for (int u2 = 0; u2 < 10; u2++) { e[u2] = __expf(attn[k][u2][vvv] - m); ssum += e[u2]; }
        float inv = 1.f / ssum;
        #pragma unroll
        for (int u2 = 0; u2 < 10; u2++) Al[k][u2][vvv] = e[u2]*inv;
    }
    __syncthreads();

    // ---- P4: F from register-resident V (waves 2,3), overwrite Q in LDS ----
    if (wv == 3) {          // F_r2l = Ar @ Vr^T, *beta -> xt0
        int k = ug;
        #pragma unroll
        for (int r = 0; r < 4; r++) {
            float scv = beta[ob+r];
            #pragma unroll
            for (int uu = 0; uu < 10; uu++) {
                float s = 0.f;
                #pragma unroll
                for (int v2 = 0; v2 < 10; v2++) s += Ar[k][uu][v2] * acc[r][v2];
                xt0[(ob+r)*LDSP + ub + uu] = s * scv;
            }
        }
    } else if (wv == 2) {   // F_l2r = Al^T @ Vl, *gamma -> xt1
        int k = ug;
        #pragma unroll
        for (int r = 0; r < 4; r++) {
            float scv = gamma[ob+r];
            #pragma unroll
            for (int vvv = 0; vvv < 10; vvv++) {
                float s = 0.f;
                #pragma unroll
                for (int u2 = 0; u2 < 10; u2++) s += Al[k][u2][vvv] * acc[r][u2];
                xt1[(ob+r)*LDSP + ub + vvv] = s * scv;
            }
        }
    }
    __syncthreads();

    // ---- P5: dynamic conv + residual + store; ALL 4 waves ----
    // wave = side*2 + half; lane covers 2 output channels x 10 pixels
    {
        int side = wv >> 1;
        int half = wv & 1;
        int oc0 = half*32 + og*2;
        const float* F  = side ? xt1 : xt0;
        const float* xg = side ? xr_g : xl_g;
        const float* wrow = g_wagg + (size_t)(side*4 + b)*4096 + oc0*64;
        float acc5[2][10];
        #pragma unroll
        for (int r = 0; r < 2; r++)
            #pragma unroll
            for (int u = 0; u < 10; u++) acc5[r][u] = 0.f;
        for (int ic = 0; ic < 16; ic++) {
            float4 wv4[2];
            #pragma unroll
            for (int r = 0; r < 2; r++)
                wv4[r] = *(const float4*)(wrow + r*64 + ic*4);
            #pragma unroll
            for (int j = 0; j < 4; j++) {
                int i = ic*4 + j;
                const float2* xp = (const float2*)(F + i*LDSP + ub);
                float2 x01 = xp[0], x23 = xp[1], x45 = xp[2], x67 = xp[3], x89 = xp[4];
                float x10[10] = {x01.x,x01.y,x23.x,x23.y,x45.x,x45.y,x67.x,x67.y,x89.x,x89.y};
                #pragma unroll
                for (int r = 0; r < 2; r++) {
                    float wf = ((const float*)&wv4[r])[j];
                    #pragma unroll
                    for (int u = 0; u < 10; u++) acc5[r][u] += wf * x10[u];
                }
            }
        }
        #pragma unroll
        for (int r = 0; r < 2; r++) {
            int o = oc0 + r;
            float bg = g_bagg[side*256 + b*64 + o];
            size_t off = (((size_t)(b*64+o)*HH + h)*WWD + w0 + ub);
            const float2* xres = (const float2*)(xg + off);
            float2* op = (float2*)(out + (size_t)side*TENSOR_ + off);
            #pragma unroll
            for (int q = 0; q < 5; q++) {
                float2 xv = xres[q];
                op[q] = make_float2(acc5[r][2*q]   + bg + xv.x,
                                    acc5[r][2*q+1] + bg + xv.y);
            }
        }
    }
}

extern "C" void kernel_launch(void* const* d_in, const int* in_sizes, int n_in,
                              void* d_out, int out_size, void* d_ws, size_t ws_size,
                              hipStream_t stream) {
    (void)in_sizes; (void)n_in; (void)out_size; (void)d_ws; (void)ws_size;
    const float* x_l  = (const float*)d_in[0];
    const float* x_r  = (const float*)d_in[1];

    gap_kernel<<<512, 256, 0, stream>>>(x_l, x_r);
    prep_kernel<<<17, 256, 0, stream>>>(
        (const float*)d_in[2],  (const float*)d_in[3],
        (const float*)d_in[4],  (const float*)d_in[5],
        (const float*)d_in[6],  (const float*)d_in[8],
        (const float*)d_in[16], (const float*)d_in[17],
        (const float*)d_in[18], (const float*)d_in[19], (const float*)d_in[21],
        (const float*)d_in[22], (const float*)d_in[23],
        (const float*)d_in[24], (const float*)d_in[25], (const float*)d_in[27],
        (const float*)d_in[20], (const float*)d_in[26]);
    main_kernel<<<BB*HH*8, 256, 0, stream>>>(x_l, x_r,
        (const float*)d_in[7],  (const float*)d_in[9],
        (const float*)d_in[10], (const float*)d_in[11],
        (const float*)d_in[12], (const float*)d_in[13],
        (const float*)d_in[14], (const float*)d_in[15],
        (float*)d_out);
}

// Round 5
// 496.874 us; speedup vs baseline: 1.3666x; 1.2888x over previous
//
#include <hip/hip_runtime.h>

typedef unsigned int u32;

#define BB 4
#define HH 180
#define WWD 320
#define HW_ 57600            // H*W
#define TENSOR_ 14745600     // B*C*H*W
#define XM 84                // xi row stride per k-pair (floats): [32][40][2]+pad
#define QS 68                // qf row stride (Q u-major [40][68])

// ---- module-scope scratch ----
__device__ __align__(16) float g_gap[512];      // [side][b][c]
__device__ __align__(16) float g_bagg[512];     // [side][b][o]
__device__ __align__(16) float g_swn[128];      // [side][o]
__device__ __align__(16) float g_sb[128];       // [side][o]
__device__ __align__(16) float g_waggT[32768];  // [side][b][i][o]  (transposed)
__device__ __align__(16) float g_w1fT[8192];    // [side][k][o] LN-folded p1 (transposed)
__device__ __align__(16) float g_p2T[8192];     // [side][k][o] p2 (transposed)

// ---------------- kernel 1: global average pool -> g_gap
__global__ __launch_bounds__(256) void gap_kernel(const float* __restrict__ xl,
                                                  const float* __restrict__ xr) {
    int job = blockIdx.x;                 // side*256 + b*64 + c
    int side = job >> 8;
    int bc = job & 255;
    const float4* p = (const float4*)((side ? xr : xl) + (size_t)bc * HW_);
    float s = 0.f;
    for (int i = threadIdx.x; i < 14400; i += 256) {
        float4 v = p[i];
        s += v.x + v.y + v.z + v.w;
    }
    #pragma unroll
    for (int off = 32; off > 0; off >>= 1) s += __shfl_down(s, off, 64);
    __shared__ float red[4];
    int lane = threadIdx.x & 63, wv = threadIdx.x >> 6;
    if (lane == 0) red[wv] = s;
    __syncthreads();
    if (threadIdx.x == 0)
        g_gap[job] = (red[0] + red[1] + red[2] + red[3]) * (1.f / 57600.f);
}

// ---------------- kernel 2: expert mixture + transposed weights + waggT + bagg
__global__ __launch_bounds__(256) void prep_kernel(
    const float* __restrict__ nlw, const float* __restrict__ nlb,
    const float* __restrict__ nrw, const float* __restrict__ nrb,
    const float* __restrict__ lp1w, const float* __restrict__ rp1w,
    const float* __restrict__ lp2w, const float* __restrict__ rp2w,
    const float* __restrict__ lf1w, const float* __restrict__ lf1b,
    const float* __restrict__ lf2w, const float* __restrict__ lf2b,
    const float* __restrict__ lfbias,
    const float* __restrict__ rf1w, const float* __restrict__ rf1b,
    const float* __restrict__ rf2w, const float* __restrict__ rf2b,
    const float* __restrict__ rfbias,
    const float* __restrict__ lfW, const float* __restrict__ rfW)
{
    __shared__ float att[2][4][3];
    int t = threadIdx.x;
    if (t < 8) {
        int side = t >> 2, b = t & 3;
        const float* f1w = side ? rf1w : lf1w;
        const float* f1b = side ? rf1b : lf1b;
        const float* f2w = side ? rf2w : lf2w;
        const float* f2bv = side ? rf2b : lf2b;
        const float* g = g_gap + side*256 + b*64;
        float a1[3];
        #pragma unroll
        for (int k = 0; k < 3; k++) {
            float s = f1b[k];
            for (int c = 0; c < 64; c++) s += g[c] * f1w[k*64 + c];
            a1[k] = fmaxf(s, 0.f);
        }
        float a2[3];
        #pragma unroll
        for (int j = 0; j < 3; j++) {
            float s = f2bv[j];
            #pragma unroll
            for (int k = 0; k < 3; k++) s += a1[k] * f2w[j*3 + k];
            a2[j] = s;
        }
        float m = fmaxf(fmaxf(a2[0], a2[1]), a2[2]);
        float e0 = __expf(a2[0]-m), e1 = __expf(a2[1]-m), e2 = __expf(a2[2]-m);
        float inv = 1.f / (e0 + e1 + e2);
        att[side][b][0] = e0*inv; att[side][b][1] = e1*inv; att[side][b][2] = e2*inv;
    }
    __syncthreads();

    if (blockIdx.x < 16) {
        int flat = blockIdx.x * 2048 + t * 8;
        int side = flat >> 14, bb = (flat >> 12) & 3, i = (flat >> 6) & 63, o0 = flat & 63;
        const float* Wp = side ? rfW : lfW;
        float a0 = att[side][bb][0], a1 = att[side][bb][1], a2 = att[side][bb][2];
        #pragma unroll
        for (int q = 0; q < 8; q++) {
            int o = o0 + q;
            g_waggT[flat+q] = a0*Wp[o*64+i] + a1*Wp[4096+o*64+i] + a2*Wp[8192+o*64+i];
        }
    } else {
        if (t < 128) {
            int side = t >> 6, o = t & 63;
            const float* w1 = side ? rp1w : lp1w;
            const float* w2 = side ? rp2w : lp2w;
            const float* nw = side ? nrw : nlw;
            const float* nb = side ? nrb : nlb;
            float s_wn = 0.f, s_b = 0.f;
            for (int i = 0; i < 64; i++) {
                float wf = w1[o*64 + i];
                float wp = wf * nw[i];
                g_w1fT[side*4096 + i*64 + o] = wp;
                g_p2T [side*4096 + i*64 + o] = w2[o*64 + i];
                s_wn += wp;
                s_b  += wf * nb[i];
            }
            g_swn[side*64 + o] = s_wn;
            g_sb[side*64 + o]  = s_b;
        }
        for (int idx = t; idx < 512; idx += 256) {
            int side = idx >> 8, r = idx & 255, b = r >> 6, o = r & 63;
            const float* bp = side ? rfbias : lfbias;
            g_bagg[idx] = att[side][b][0]*bp[o]
                        + att[side][b][1]*bp[64+o]
                        + att[side][b][2]*bp[128+o];
        }
    }
}

// ---------------- kernel 3: fused LN->proj->cross-attn->dynamic conv->residual
// block = one (b,h) row x 4 width-chunks (40 px); 4 waves.
// xi: x in k-pair-interleaved layout [m=k/2][px][k&1], stride XM=84. Lives whole kernel.
// qf: Q u-major [u][QS=68] for attention, then reused as F k-pair layout [m][px][par].
__global__ __launch_bounds__(256, 3) void main_kernel(
    const float* __restrict__ xl_g, const float* __restrict__ xr_g,
    const float* __restrict__ lp1b, const float* __restrict__ rp1b,
    const float* __restrict__ lp2b, const float* __restrict__ rp2b,
    const float* __restrict__ beta, const float* __restrict__ gamma,
    float* __restrict__ out)
{
    __shared__ __align__(16) float xi0[2688];
    __shared__ __align__(16) float xi1[2688];
    __shared__ __align__(16) float qf0[2720];
    __shared__ __align__(16) float qf1[2720];
    __shared__ float attn[4][10][10];
    __shared__ float Ar[4][10][10];   // softmax over v
    __shared__ float Al[4][10][10];   // softmax over u
    __shared__ float muA[40], rsA[40], muB[40], rsB[40];

    int t = threadIdx.x;
    int wv = t >> 6, lane = t & 63;
    int bid = blockIdx.x;
    int b  = bid / (HH*8);
    int r0 = bid % (HH*8);
    int h  = r0 / 8;
    int g  = r0 % 8;
    int w0 = g * 40;

    // ---- P0: stage x into k-pair-interleaved LDS ----
    for (int idx = t; idx < 1280; idx += 256) {
        int tensor = idx / 640;
        int r2 = idx - tensor*640;
        int c = r2 / 10, seg = r2 - c*10;          // seg: 10 float4 per 40-px row
        const float* src = tensor ? xr_g : xl_g;
        float4 v = *(const float4*)(src + (((size_t)(b*64+c)*HH + h)*WWD + w0 + seg*4));
        float* dst = (tensor ? xi1 : xi0) + (c >> 1)*XM + (seg*4)*2 + (c & 1);
        dst[0] = v.x; dst[2] = v.y; dst[4] = v.z; dst[6] = v.w;
    }
    __syncthreads();

    // ---- P1: LN stats, 20 lanes x 4 waves cover 2 sides x 40 px ----
    if (lane < 20) {
        int side = wv >> 1;
        int u = (wv & 1)*20 + lane;
        const float* xx = side ? xi1 : xi0;
        float s = 0.f, s2 = 0.f;
        for (int m = 0; m < 32; m++) {
            float v0 = xx[m*XM + u*2];
            float v1 = xx[m*XM + u*2 + 1];
            s += v0 + v1; s2 += v0*v0 + v1*v1;
        }
        float mu = s * (1.f/64.f);
        float var = fmaxf(s2 * (1.f/64.f) - mu*mu, 0.f);
        float rs = rsqrtf(var + 1e-6f);
        if (side) { muB[u] = mu; rsB[u] = rs; } else { muA[u] = mu; rsA[u] = rs; }
    }
    __syncthreads();

    // ---- P2: 4 GEMMs (Ql,Qr,Vl,Vr), o-tile 8 x u-tile 5, k-paired ----
    int og = lane & 7, ug = lane >> 3;
    int ob = og * 8, ub = ug * 5;

    float acc[8][5];
    #pragma unroll
    for (int r = 0; r < 8; r++)
        #pragma unroll
        for (int j = 0; j < 5; j++) acc[r][j] = 0.f;

    {
        const float* wT; const float* xs;
        switch (wv) {
            case 0:  wT = g_w1fT;        xs = xi0; break;
            case 1:  wT = g_w1fT + 4096; xs = xi1; break;
            case 2:  wT = g_p2T;         xs = xi0; break;
            default: wT = g_p2T + 4096;  xs = xi1; break;
        }
        for (int m = 0; m < 32; m++) {
            const float* wp = wT + m*128;
            float4 wa0 = *(const float4*)(wp + ob);
            float4 wa1 = *(const float4*)(wp + ob + 4);
            float4 wb0 = *(const float4*)(wp + 64 + ob);
            float4 wb1 = *(const float4*)(wp + 64 + ob + 4);
            float2 xv[5];
            const float* xrow = xs + m*XM + ub*2;
            #pragma unroll
            for (int j = 0; j < 5; j++) xv[j] = *(const float2*)(xrow + j*2);
            float wa[8] = {wa0.x,wa0.y,wa0.z,wa0.w, wa1.x,wa1.y,wa1.z,wa1.w};
            float wb[8] = {wb0.x,wb0.y,wb0.z,wb0.w, wb1.x,wb1.y,wb1.z,wb1.w};
            #pragma unroll
            for (int r = 0; r < 8; r++)
                #pragma unroll
                for (int j = 0; j < 5; j++) {
                    acc[r][j] = fmaf(wa[r], xv[j].x, acc[r][j]);
                    acc[r][j] = fmaf(wb[r], xv[j].y, acc[r][j]);
                }
        }
    }

    if (wv < 2) {   // Q epilogue (LN fold) -> qf u-major
        const float* mu  = wv ? muB : muA;
        const float* rs  = wv ? rsB : rsA;
        const float* p1b = wv ? rp1b : lp1b;
        float* qdst = wv ? qf1 : qf0;
        float swl[8], sbl[8];
        #pragma unroll
        for (int r = 0; r < 8; r++) {
            swl[r] = g_swn[wv*64 + ob + r];
            sbl[r] = g_sb[wv*64 + ob + r] + p1b[ob + r];
        }
        #pragma unroll
        for (int j = 0; j < 5; j++) {
            int u = ub + j;
            float rsv = rs[u], muv = mu[u];
            float e[8];
            #pragma unroll
            for (int r = 0; r < 8; r++)
                e[r] = rsv*(acc[r][j] - muv*swl[r]) + sbl[r];
            *(float4*)(qdst + u*QS + ob)     = make_float4(e[0],e[1],e[2],e[3]);
            *(float4*)(qdst + u*QS + ob + 4) = make_float4(e[4],e[5],e[6],e[7]);
        }
    } else {        // V: add bias, stay in registers
        const float* p2b = (wv == 2) ? lp2b : rp2b;
        #pragma unroll
        for (int r = 0; r < 8; r++) {
            float bv = p2b[ob + r];
            #pragma unroll
            for (int j = 0; j < 5; j++) acc[r][j] += bv;
        }
    }
    __syncthreads();

    // ---- P3: block-diag attention scores; wave = chunk ----
    for (int p = lane; p < 100; p += 64) {
        int uu = p / 10, vv = p - (p/10)*10;
        const float4* ra = (const float4*)(qf0 + (wv*10 + uu)*QS);
        const float4* rb = (const float4*)(qf1 + (wv*10 + vv)*QS);
        float s = 0.f;
        #pragma unroll
        for (int cc = 0; cc < 16; cc++) {
            float4 a = ra[cc], q = rb[cc];
            s += a.x*q.x + a.y*q.y + a.z*q.z + a.w*q.w;
        }
        attn[wv][uu][vv] = s * 0.125f;
    }
    __syncthreads();

    if (t < 40) {                      // softmax over v -> Ar
        int k = t / 10, uu = t - (t/10)*10;
        float m = attn[k][uu][0];
        #pragma unroll
        for (int v2 = 1; v2 < 10; v2++) m = fmaxf(m, attn[k][uu][v2]);
        float e[10]; float ssum = 0.f;
        #pragma unroll
        for (int v2 = 0; v2 < 10; v2++) { e[v2] = __expf(attn[k][uu][v2] - m); ssum += e[v2]; }
        float inv = 1.f / ssum;
        #pragma unroll
        for (int v2 = 0; v2 < 10; v2++) Ar[k][uu][v2] = e[v2]*inv;
    } else if (t >= 64 && t < 104) {   // softmax over u -> Al
        int t2 = t - 64;
        int k = t2 / 10, vv = t2 - (t2/10)*10;
        float m = attn[k][0][vv];
        #pragma unroll
        for (int u2 = 1; u2 < 10; u2++) m = fmaxf(m, attn[k][u2][vv]);
        float e[10]; float ssum = 0.f;
        #pragma unroll
        for (int u2 = 0; u2 < 10; u2++) { e[u2] = __expf(attn[k][u2][vv] - m); ssum += e[u2]; }
        float inv = 1.f / ssum;
        #pragma unroll
        for (int u2 = 0; u2 < 10; u2++) Al[k][u2][vv] = e[u2]*inv;
    }
    __syncthreads();

    // ---- P4: F from register V, half-exchange via shfl; write k-paired into qf ----
    if (wv == 3) {          // Vr -> F_r2l*beta -> qf0 (for side-0 output)
        int k = ug >> 1, half = ug & 1, vb = half*5;
        float sc[8];
        #pragma unroll
        for (int r = 0; r < 8; r++) sc[r] = beta[ob + r];
        #pragma unroll
        for (int j2 = 0; j2 < 5; j2++) {
            int u1 = vb + j2;          // my output slice
            int u2 = 5 - vb + j2;      // partner's output slice
            float a1[5], a2[5];
            #pragma unroll
            for (int j = 0; j < 5; j++) { a1[j] = Ar[k][u1][vb+j]; a2[j] = Ar[k][u2][vb+j]; }
            #pragma unroll
            for (int r = 0; r < 8; r++) {
                float sA = 0.f, sB = 0.f;
                #pragma unroll
                for (int j = 0; j < 5; j++) {
                    sA = fmaf(a1[j], acc[r][j], sA);
                    sB = fmaf(a2[j], acc[r][j], sB);
                }
                float recv = __shfl_xor(sB, 8, 64);
                int o = ob + r;
                qf0[(o>>1)*XM + (k*10 + u1)*2 + (o&1)] = (sA + recv) * sc[r];
            }
        }
    } else if (wv == 2) {   // Vl -> F_l2r*gamma -> qf1 (for side-1 output)
        int k = ug >> 1, half = ug & 1, vb = half*5;
        float sc[8];
        #pragma unroll
        for (int r = 0; r < 8; r++) sc[r] = gamma[ob + r];
        #pragma unroll
        for (int j2 = 0; j2 < 5; j2++) {
            int u1 = vb + j2;
            int u2 = 5 - vb + j2;
            float a1[5], a2[5];
            #pragma unroll
            for (int j = 0; j < 5; j++) { a1[j] = Al[k][vb+j][u1]; a2[j] = Al[k][vb+j][u2]; }
            #pragma unroll
            for (int r = 0; r < 8; r++) {
                float sA = 0.f, sB = 0.f;
                #pragma unroll
                for (int j = 0; j < 5; j++) {
                    sA = fmaf(a1[j], acc[r][j], sA);
                    sB = fmaf(a2[j], acc[r][j], sB);
                }
                float recv = __shfl_xor(sB, 8, 64);
                int o = ob + r;
                qf1[(o>>1)*XM + (k*10 + u1)*2 + (o&1)] = (sA + recv) * sc[r];
            }
        }
    }
    __syncthreads();

    // ---- P5: dynamic conv + residual(LDS) + store; waves 0,1 (wave = side) ----
    if (wv < 2) {
        const float* Fb   = wv ? qf1 : qf0;
        const float* xres = wv ? xi1 : xi0;
        const float* wrow = g_waggT + (size_t)(wv*4 + b)*4096;
        float acc5[8][5];
        #pragma unroll
        for (int r = 0; r < 8; r++)
            #pragma unroll
            for (int j = 0; j < 5; j++) acc5[r][j] = 0.f;
        for (int m = 0; m < 32; m++) {
            const float* wp = wrow + m*128;
            float4 wa0 = *(const float4*)(wp + ob);
            float4 wa1 = *(const float4*)(wp + ob + 4);
            float4 wb0 = *(const float4*)(wp + 64 + ob);
            float4 wb1 = *(const float4*)(wp + 64 + ob + 4);
            float2 xv[5];
            const float* frow = Fb + m*XM + ub*2;
            #pragma unroll
            for (int j = 0; j < 5; j++) xv[j] = *(const float2*)(frow + j*2);
            float wa[8] = {wa0.x,wa0.y,wa0.z,wa0.w, wa1.x,wa1.y,wa1.z,wa1.w};
            float wb[8] = {wb0.x,wb0.y,wb0.z,wb0.w, wb1.x,wb1.y,wb1.z,wb1.w};
            #pragma unroll
            for (int r = 0; r < 8; r++)
                #pragma unroll
                for (int j = 0; j < 5; j++) {
                    acc5[r][j] = fmaf(wa[r], xv[j].x, acc5[r][j]);
                    acc5[r][j] = fmaf(wb[r], xv[j].y, acc5[r][j]);
                }
        }
        #pragma unroll
        for (int r = 0; r < 8; r++) {
            int o = ob + r;
            float bg = g_bagg[wv*256 + b*64 + o];
            float* op = out + (size_t)wv*TENSOR_ + (((size_t)(b*64+o)*HH + h)*WWD + w0 + ub);
            #pragma unroll
            for (int j = 0; j < 5; j++)
                op[j] = acc5[r][j] + bg + xres[(o>>1)*XM + (ub+j)*2 + (o&1)];
        }
    }
}

extern "C" void kernel_launch(void* const* d_in, const int* in_sizes, int n_in,
                              void* d_out, int out_size, void* d_ws, size_t ws_size,
                              hipStream_t stream) {
    (void)in_sizes; (void)n_in; (void)out_size; (void)d_ws; (void)ws_size;
    const float* x_l = (const float*)d_in[0];
    const float* x_r = (const float*)d_in[1];

    gap_kernel<<<512, 256, 0, stream>>>(x_l, x_r);
    prep_kernel<<<17, 256, 0, stream>>>(
        (const float*)d_in[2],  (const float*)d_in[3],
        (const float*)d_in[4],  (const float*)d_in[5],
        (const float*)d_in[6],  (const float*)d_in[8],
        (const float*)d_in[10], (const float*)d_in[12],
        (const float*)d_in[16], (const float*)d_in[17],
        (const float*)d_in[18], (const float*)d_in[19], (const float*)d_in[21],
        (const float*)d_in[22], (const float*)d_in[23],
        (const float*)d_in[24], (const float*)d_in[25], (const float*)d_in[27],
        (const float*)d_in[20], (const float*)d_in[26]);
    main_kernel<<<BB*HH*8, 256, 0, stream>>>(x_l, x_r,
        (const float*)d_in[7],  (const float*)d_in[9],
        (const float*)d_in[11], (const float*)d_in[13],
        (const float*)d_in[14], (const float*)d_in[15],
        (float*)d_out);
}